// Round 18
// baseline (615.030 us; speedup 1.0000x reference)
//
#include <hip/hip_runtime.h>
#include <math.h>

typedef __bf16 bf16_t;
typedef __attribute__((ext_vector_type(16))) float f32x16;
typedef __attribute__((ext_vector_type(8))) __bf16 v8bf;
typedef __attribute__((ext_vector_type(4))) __bf16 v4bf;

// offset=0 ALWAYS: LDS-DMA offset imm shifts the LDS destination too (R5 post-mortem).
#define GLLDS(g, l)                                                           \
  __builtin_amdgcn_global_load_lds(                                           \
      (const __attribute__((address_space(1))) void*)(g),                     \
      (__attribute__((address_space(3))) void*)(l), 16, 0, 0)
// opaque pointer tie: prevents folding constant steps into the LDS-DMA offset imm.
#define OPQ(p) asm volatile("" : "+v"(p))

// ---------------- diagnostic sentinel ----------------
__global__ void sentinel_kernel(float* o, float v) { o[0] = v; }

// ---------------- pack kernels ----------------
__global__ __launch_bounds__(256) void pack_x_kernel(
    const float* __restrict__ xa, const float* __restrict__ xb,
    bf16_t* __restrict__ xcat, int n4)
{
  int i = blockIdx.x * 256 + threadIdx.x;
  if (i >= n4) return;
  float4 a = reinterpret_cast<const float4*>(xa)[i];
  float4 b = reinterpret_cast<const float4*>(xb)[i];
  long e = (long)i * 4;
  long m = e >> 10;
  int  d = (int)(e & 1023);
  v4bf av = { (bf16_t)a.x, (bf16_t)a.y, (bf16_t)a.z, (bf16_t)a.w };
  v4bf bv = { (bf16_t)b.x, (bf16_t)b.y, (bf16_t)b.z, (bf16_t)b.w };
  *reinterpret_cast<v4bf*>(xcat + m * 2048 + d)        = av;
  *reinterpret_cast<v4bf*>(xcat + m * 2048 + 1024 + d) = bv;
}

// outA[n] = [wa[n,:] | j2*wb[n,:]] ; outB[n] = [wb[n,:] | wa[n,:]]
__global__ __launch_bounds__(256) void pack_w_kernel(
    const float* __restrict__ wa, const float* __restrict__ wb,
    bf16_t* __restrict__ outA, bf16_t* __restrict__ outB, float j2)
{
  int i = blockIdx.x * 256 + threadIdx.x;   // 0..262143, exact
  float4 a = reinterpret_cast<const float4*>(wa)[i];
  float4 b = reinterpret_cast<const float4*>(wb)[i];
  long e = (long)i * 4;
  long n = e >> 10;
  int  k = (int)(e & 1023);
  v4bf av = { (bf16_t)a.x, (bf16_t)a.y, (bf16_t)a.z, (bf16_t)a.w };
  v4bf bv = { (bf16_t)b.x, (bf16_t)b.y, (bf16_t)b.z, (bf16_t)b.w };
  v4bf jb = { (bf16_t)(j2*b.x), (bf16_t)(j2*b.y), (bf16_t)(j2*b.z), (bf16_t)(j2*b.w) };
  *reinterpret_cast<v4bf*>(outA + n * 2048 + k)        = av;
  *reinterpret_cast<v4bf*>(outA + n * 2048 + 1024 + k) = jb;
  *reinterpret_cast<v4bf*>(outB + n * 2048 + k)        = bv;
  *reinterpret_cast<v4bf*>(outB + n * 2048 + 1024 + k) = av;
}

// fused 4-projection weight pack: blockIdx.y selects projection.
struct WPack {
  const float* wa[4];
  const float* wb[4];
  bf16_t* oA[4];
  bf16_t* oB[4];
};
__global__ __launch_bounds__(256) void pack_w4_kernel(WPack wp, float j2)
{
  const int p = blockIdx.y;
  const float* wa = wp.wa[p];
  const float* wb = wp.wb[p];
  bf16_t* outA = wp.oA[p];
  bf16_t* outB = wp.oB[p];
  int i = blockIdx.x * 256 + threadIdx.x;   // 0..262143, exact
  float4 a = reinterpret_cast<const float4*>(wa)[i];
  float4 b = reinterpret_cast<const float4*>(wb)[i];
  long e = (long)i * 4;
  long n = e >> 10;
  int  k = (int)(e & 1023);
  v4bf av = { (bf16_t)a.x, (bf16_t)a.y, (bf16_t)a.z, (bf16_t)a.w };
  v4bf bv = { (bf16_t)b.x, (bf16_t)b.y, (bf16_t)b.z, (bf16_t)b.w };
  v4bf jb = { (bf16_t)(j2*b.x), (bf16_t)(j2*b.y), (bf16_t)(j2*b.z), (bf16_t)(j2*b.w) };
  *reinterpret_cast<v4bf*>(outA + n * 2048 + k)        = av;
  *reinterpret_cast<v4bf*>(outA + n * 2048 + 1024 + k) = jb;
  *reinterpret_cast<v4bf*>(outB + n * 2048 + k)        = bv;
  *reinterpret_cast<v4bf*>(outB + n * 2048 + 1024 + k) = av;
}

// ---------------- 256x128 bf16 GEMM, 4 waves (2Mx2N), 2 blocks/CU ----------
// R18: cross-block overlap at NEUTRAL LDS ratio (R14 post-mortem math:
// LDS-read B/FLOP = 22.9, same as R12's best). Per-wave 128x64 (acc=128,
// same as R12 -> ~128 VGPR), BK=32, 2-slot ring = 48 KiB -> 2 independent
// blocks/CU (independent barriers; m114 MFMA||LDS overlap across blocks).
// Ledger (R12-validated): tile t reads slot t&1, stages t+1 into other slot;
// RAW via tile-end vmcnt(0)+barrier; WAR via prior barrier.
// LDS per slot: [A 256x32 | B 128x32]; chunk c (16B) of row R stored at
// c ^ ((R>>1)&3) (swizzle on GLOBAL source col, rule #21).
// A/B operand: row=lane&31, k=(lane>>5)*8+e (+16/slice). C/D: col=lane&31,
// row=(reg&3)+8*(reg>>2)+4*(lane>>5)  [guide m74/m101; R8-validated].
// EPI 0: QKV-routed, Kc interleaved. EPI 1: scores+magnitude (balanced).
// EPI 2: PV bf16. EPI 3: O fp32 +bias.
template<int EPI>
__global__ __launch_bounds__(256, 2) void gemm256_kernel(
    const bf16_t* __restrict__ A, const bf16_t* __restrict__ B,
    int K, long lda, long ldb, long bsA, long bsB,
    void* __restrict__ o0p, void* __restrict__ o1p, void* __restrict__ o2p,
    const float* __restrict__ bb0, const float* __restrict__ bb1,
    const float* __restrict__ bb2, const float* __restrict__ bb3,
    const float* __restrict__ bb4, const float* __restrict__ bb5,
    float scl)
{
  __shared__ __align__(16) bf16_t lds[24576];  // 2 slots x (A[256][32] | B[128][32])
  const int tid  = threadIdx.x;
  const int wid  = tid >> 6;      // 0..3
  const int lane = tid & 63;
  const int wm = wid >> 1;        // 0..1 (128-row half)
  const int wn = wid & 1;         // 0..1 (64-col half)

  const long row0 = (long)blockIdx.y * 256;
  const long col0 = (long)blockIdx.x * 128;
  const int z = blockIdx.z;
  const bf16_t* Ab = A + (long)z * bsA + row0 * lda;
  const bf16_t* Bb = B + (long)z * bsB + col0 * ldb;

  // staging: thread t covers row (t>>2) (+64 per GLLDS index), chunk t&3 of a
  // 32-el row; swizzled GLOBAL source col = ((t&3)^((t>>3)&3))*8 (store key
  // (row>>1)&3 with row = i*64 + (t>>2) -> key = (t>>3)&3). LINEAR LDS dest.
  const int srow = tid >> 2;
  const int scol = ((tid & 3) ^ ((tid >> 3) & 3)) * 8;
  const int dbase = wid * 512;   // wave-uniform el offset within a 2048-el chunk

  // rolling staging pointers (advance 32 el per staged tile, opaque each step)
  const bf16_t* sA0 = Ab + (long)srow * lda + scol;
  const bf16_t* sA1 = Ab + (long)(srow + 64) * lda + scol;
  const bf16_t* sA2 = Ab + (long)(srow + 128) * lda + scol;
  const bf16_t* sA3 = Ab + (long)(srow + 192) * lda + scol;
  const bf16_t* sB0 = Bb + (long)srow * ldb + scol;
  const bf16_t* sB1 = Bb + (long)(srow + 64) * ldb + scol;

  // ds_read bases; stored chunk = (s*2 + kg2) ^ ((r32>>1)&3)
  const int r32 = lane & 31;
  const int kg2 = lane >> 5;
  const int key = (r32 >> 1) & 3;
  const bf16_t *pA[2], *pB[2];
#pragma unroll
  for (int s = 0; s < 2; ++s) {
    const int ch = ((s * 2 + kg2) ^ key) * 8;
    pA[s] = lds + (wm * 128 + r32) * 32 + ch;
    pB[s] = lds + 8192 + (wn * 64 + r32) * 32 + ch;
  }

  f32x16 acc[4][2];
#pragma unroll
  for (int i = 0; i < 4; ++i)
#pragma unroll
    for (int j = 0; j < 2; ++j)
#pragma unroll
      for (int e = 0; e < 16; ++e) acc[i][j][e] = 0.f;

  const int T = K >> 5;   // BK=32; K=2048 -> T=64 (even)

  // prologue: stage tile 0 into slot 0 (6 GLLDS: A=4x4KB, B=2x4KB), drain
  GLLDS(sA0, lds + dbase);
  GLLDS(sA1, lds + 2048 + dbase);
  GLLDS(sA2, lds + 4096 + dbase);
  GLLDS(sA3, lds + 6144 + dbase);
  GLLDS(sB0, lds + 8192 + dbase);
  GLLDS(sB1, lds + 10240 + dbase);
  sA0 += 32; sA1 += 32; sA2 += 32; sA3 += 32; sB0 += 32; sB1 += 32;
  OPQ(sA0); OPQ(sA1); OPQ(sA2); OPQ(sA3); OPQ(sB0); OPQ(sB1);
  asm volatile("s_waitcnt vmcnt(0)" ::: "memory");
  __builtin_amdgcn_sched_barrier(0);
  __builtin_amdgcn_s_barrier();

  // One K-tile (BK=32): 12 ds_read_b128 + 6 stages(t+1) + 16 MFMA(32x32x16),
  // single tile-end vmcnt(0)+barrier. U literal 0/1; stages go to slot 1-U.
#define TILE_BODY(U, PF)                                                       \
  {                                                                            \
    const int so_ = (U) * 12288;                                               \
    const int ns_ = (1 - (U)) * 12288;                                         \
    v8bf a_[4][2], b_[2][2];                                                   \
    _Pragma("unroll") for (int g = 0; g < 2; ++g)                              \
      _Pragma("unroll") for (int ss = 0; ss < 2; ++ss)                         \
        b_[g][ss] = *reinterpret_cast<const v8bf*>(pB[ss] + so_ + g * 1024);   \
    _Pragma("unroll") for (int f = 0; f < 4; ++f)                              \
      _Pragma("unroll") for (int ss = 0; ss < 2; ++ss)                         \
        a_[f][ss] = *reinterpret_cast<const v8bf*>(pA[ss] + so_ + f * 1024);   \
    if (PF) {                                                                  \
      GLLDS(sA0, lds + ns_ + dbase);                                           \
      GLLDS(sA1, lds + ns_ + 2048 + dbase);                                    \
      GLLDS(sA2, lds + ns_ + 4096 + dbase);                                    \
      GLLDS(sA3, lds + ns_ + 6144 + dbase);                                    \
    }                                                                          \
    __builtin_amdgcn_s_setprio(1);                                             \
    _Pragma("unroll") for (int f = 0; f < 4; ++f)                              \
      _Pragma("unroll") for (int g = 0; g < 2; ++g)                            \
        acc[f][g] = __builtin_amdgcn_mfma_f32_32x32x16_bf16(a_[f][0], b_[g][0], acc[f][g], 0, 0, 0); \
    __builtin_amdgcn_s_setprio(0);                                             \
    if (PF) {                                                                  \
      GLLDS(sB0, lds + ns_ + 8192 + dbase);                                    \
      GLLDS(sB1, lds + ns_ + 10240 + dbase);                                   \
      sA0 += 32; sA1 += 32; sA2 += 32; sA3 += 32; sB0 += 32; sB1 += 32;        \
      OPQ(sA0); OPQ(sA1); OPQ(sA2); OPQ(sA3); OPQ(sB0); OPQ(sB1);              \
    }                                                                          \
    __builtin_amdgcn_s_setprio(1);                                             \
    _Pragma("unroll") for (int f = 0; f < 4; ++f)                              \
      _Pragma("unroll") for (int g = 0; g < 2; ++g)                            \
        acc[f][g] = __builtin_amdgcn_mfma_f32_32x32x16_bf16(a_[f][1], b_[g][1], acc[f][g], 0, 0, 0); \
    __builtin_amdgcn_s_setprio(0);                                             \
    asm volatile("s_waitcnt vmcnt(0)" ::: "memory");                           \
    __builtin_amdgcn_sched_barrier(0);                                         \
    __builtin_amdgcn_s_barrier();                                              \
  }

  // main: tiles 0..T-3 (all stage the next tile)
  for (int tb = 0; tb < T - 2; tb += 2) {
    TILE_BODY(0, 1)
    TILE_BODY(1, 1)
  }
  // tail: tile T-2 stages T-1; tile T-1 stages nothing
  TILE_BODY(0, 1)
  TILE_BODY(1, 0)
#undef TILE_BODY

  // epilogue: 32x32 C/D layout col=lane&31, row=(reg&3)+8*(reg>>2)+4*(lane>>5)
  const int hi = lane >> 5;
#pragma unroll
  for (int fm = 0; fm < 4; ++fm) {
#pragma unroll
    for (int fn = 0; fn < 2; ++fn) {
      const f32x16 v = acc[fm][fn];
      const long rowb = row0 + wm * 128 + fm * 32 + 4 * hi;
      const long col  = col0 + wn * 64 + fn * 32 + r32;
      if constexpr (EPI == 0) {
        const int  seg = (int)(col >> 10);   // uniform per block (128 | 1024)
        const long c   = col & 1023;
        bf16_t* Q  = (bf16_t*)o0p;
        bf16_t* Kc = (bf16_t*)o1p;
        bf16_t* Vc = (bf16_t*)o2p;
        switch (seg) {
          case 0: { const float bv = bb0[c];
#pragma unroll
            for (int r = 0; r < 16; ++r) {
              const long row = rowb + (r & 3) + 8 * (r >> 2);
              Q[row * 2048 + c] = (bf16_t)((v[r] + bv) * 0.03125f);
            } } break;
          case 1: { const float bv = bb1[c];
#pragma unroll
            for (int r = 0; r < 16; ++r) {
              const long row = rowb + (r & 3) + 8 * (r >> 2);
              Q[row * 2048 + 1024 + c] = (bf16_t)((v[r] + bv) * 0.03125f);
            } } break;
          case 2: { const float bv = bb2[c];
            // interleaved Kc: row 2t = K1 token t, row 2t+1 = K2 token t
#pragma unroll
            for (int r = 0; r < 16; ++r) {
              const long row = rowb + (r & 3) + 8 * (r >> 2);
              const long kb2 = (row >> 11) * 8388608 + (row & 2047) * 4096;
              const float w = v[r] + bv;
              Kc[kb2 + c]               = (bf16_t)w;          // K1 = [Ka | .]
              Kc[kb2 + 2048 + 1024 + c] = (bf16_t)w;          // K2 = [. | Ka]
            } } break;
          case 3: { const float bv = bb3[c];
#pragma unroll
            for (int r = 0; r < 16; ++r) {
              const long row = rowb + (r & 3) + 8 * (r >> 2);
              const long kb2 = (row >> 11) * 8388608 + (row & 2047) * 4096;
              const float w = v[r] + bv;
              Kc[kb2 + 2048 + c] = (bf16_t)w;                 // K2 = [Kb | .]
              Kc[kb2 + 1024 + c] = (bf16_t)(scl * w);         // K1 = [. | -c2*Kb]
            } } break;
          case 4: { const float bv = bb4[c];
#pragma unroll
            for (int r = 0; r < 16; ++r) {
              const long row = rowb + (r & 3) + 8 * (r >> 2);
              Vc[row * 2048 + c] = (bf16_t)(v[r] + bv);
            } } break;
          default: { const float bv = bb5[c];
#pragma unroll
            for (int r = 0; r < 16; ++r) {
              const long row = rowb + (r & 3) + 8 * (r >> 2);
              Vc[row * 2048 + 1024 + c] = (bf16_t)(v[r] + bv);
            } } break;
        }
      } else if constexpr (EPI == 1) {
        // interleaved scores: col even = sa, odd = sb; pair lanes (l, l^1)
        // hold identical mg after shfl -> balanced: even writes r0-7, odd r8-15.
        bf16_t* dst = (bf16_t*)o0p;
        const long tt = col >> 1;
        float mg[16];
#pragma unroll
        for (int r = 0; r < 16; ++r) {
          const float x = v[r];
          const float p = __shfl_xor(x, 1);
          mg[r] = sqrtf(x * x + p * p);
        }
        const int rb2 = (lane & 1) * 8;
#pragma unroll
        for (int rr2 = 0; rr2 < 8; ++rr2) {
          const int r = rb2 + rr2;
          const long row = rowb + (r & 3) + 8 * (r >> 2);
          dst[(long)z * 4194304 + row * 2048 + tt] = (bf16_t)mg[r];
        }
      } else if constexpr (EPI == 2) {
#pragma unroll
        for (int r = 0; r < 16; ++r) {
          const long row = rowb + (r & 3) + 8 * (r >> 2);
          ((bf16_t*)o0p)[(long)z * 4194304 + row * 2048 + col] = (bf16_t)v[r];
        }
      } else {
        const int  seg = (int)(col >> 10);
        const long c   = col & 1023;
        float* dst = seg ? (float*)o1p : (float*)o0p;
        const float bv = seg ? bb1[c] : bb0[c];
#pragma unroll
        for (int r = 0; r < 16; ++r) {
          const long row = rowb + (r & 3) + 8 * (r >> 2);
          dst[row * 1024 + c] = v[r] + bv;
        }
      }
    }
  }
}

// ---------------- V transpose (fused both halves via blockIdx.z) ----------------
__global__ __launch_bounds__(256) void transpose_v_kernel(
    const bf16_t* __restrict__ src, bf16_t* __restrict__ dst)
{
  __shared__ bf16_t t[64][65];
  const int tid = threadIdx.x;
  const int off = blockIdx.z * 1024;
  const long c0 = (long)blockIdx.x * 64;
  const long g0 = (long)blockIdx.y * 64;
#pragma unroll
  for (int it = 0; it < 16; ++it) {
    int idx = it * 256 + tid;
    int r = idx >> 6, c = idx & 63;
    t[r][c] = src[(g0 + r) * 2048 + off + c0 + c];
  }
  __syncthreads();
  const long b  = g0 >> 11;
  const long t0 = g0 & 2047;
#pragma unroll
  for (int it = 0; it < 16; ++it) {
    int idx = it * 256 + tid;
    int nr = idx >> 6, tc = idx & 63;
    dst[b * 4194304 + (off + c0 + nr) * 2048 + t0 + tc] = t[tc][nr];
  }
}

// ---------------- softmax over precomputed magnitude (in-place safe) ----------------
__global__ __launch_bounds__(256) void softmax_kernel(
    const bf16_t* __restrict__ mag, bf16_t* __restrict__ attn)
{
  const int tid = threadIdx.x;
  const long base = (long)blockIdx.x * 2048;
  v4bf m0 = *reinterpret_cast<const v4bf*>(mag + base + tid * 4);
  v4bf m1 = *reinterpret_cast<const v4bf*>(mag + base + 1024 + tid * 4);
  float r[8];
#pragma unroll
  for (int k = 0; k < 4; ++k) r[k] = (float)m0[k];
#pragma unroll
  for (int k = 0; k < 4; ++k) r[4 + k] = (float)m1[k];
  float m = r[0];
#pragma unroll
  for (int k = 1; k < 8; ++k) m = fmaxf(m, r[k]);
#pragma unroll
  for (int off = 32; off > 0; off >>= 1) m = fmaxf(m, __shfl_xor(m, off));
  __shared__ float red[8];
  if ((tid & 63) == 0) red[tid >> 6] = m;
  __syncthreads();
  m = fmaxf(fmaxf(red[0], red[1]), fmaxf(red[2], red[3]));
  float p[8], s = 0.f;
#pragma unroll
  for (int k = 0; k < 8; ++k) { p[k] = __expf(r[k] - m); s += p[k]; }
#pragma unroll
  for (int off = 32; off > 0; off >>= 1) s += __shfl_xor(s, off);
  if ((tid & 63) == 0) red[4 + (tid >> 6)] = s;
  __syncthreads();
  const float inv = 1.f / (red[4] + red[5] + red[6] + red[7]);
  v4bf o0 = { (bf16_t)(p[0]*inv), (bf16_t)(p[1]*inv), (bf16_t)(p[2]*inv), (bf16_t)(p[3]*inv) };
  v4bf o1 = { (bf16_t)(p[4]*inv), (bf16_t)(p[5]*inv), (bf16_t)(p[6]*inv), (bf16_t)(p[7]*inv) };
  *reinterpret_cast<v4bf*>(attn + base + tid * 4)        = o0;
  *reinterpret_cast<v4bf*>(attn + base + 1024 + tid * 4) = o1;
}

// ---------------- host ----------------
extern "C" void kernel_launch(void* const* d_in, const int* in_sizes, int n_in,
                              void* d_out, int out_size, void* d_ws, size_t ws_size,
                              hipStream_t stream)
{
  (void)in_sizes; (void)n_in; (void)out_size;
  const float* xa = (const float*)d_in[0];
  const float* xb = (const float*)d_in[1];
  const float *w_a[4], *w_b[4], *b_a[4], *b_b[4];
  for (int p = 0; p < 4; ++p) {
    w_a[p] = (const float*)d_in[2 + p*4 + 0];
    w_b[p] = (const float*)d_in[2 + p*4 + 1];
    b_a[p] = (const float*)d_in[2 + p*4 + 2];
    b_b[p] = (const float*)d_in[2 + p*4 + 3];
  }
  float* out = (float*)d_out;
  const float neg_c2 = (float)(-cos(2.0));

  // ---- adaptive workspace tiers (identical thresholds to passing rounds) ----
  const size_t WFULL = 33554432ull;   // 8 weight slots of [1024,2048] bf16
  const size_t WQKV  = 25165824ull;   // 6 slots (low tier: O re-packed over QKV)
  int NB = 0; bool fullW = true;
  if      (ws_size >= WFULL + 6ull * 4ull * 8388608ull) NB = 4;               // 224 MiB
  else if (ws_size >= WFULL + 6ull * 2ull * 8388608ull) NB = 2;               // 128 MiB
  else if (ws_size >= WFULL + 6ull * 1ull * 8388608ull) NB = 1;               //  80 MiB
  else if (ws_size >= WQKV  + 6ull * 1ull * 8388608ull) { NB = 1; fullW = false; } // 72 MiB
  else { sentinel_kernel<<<1, 1, 0, stream>>>(out, (float)ws_size); return; }

  char* ws = (char*)d_ws;
  const size_t wbytes = fullW ? WFULL : WQKV;
  const size_t RB = (size_t)NB * 8388608ull;
  bf16_t* Wqkv = (bf16_t*)ws;                            // 6 x [1024,2048]
  bf16_t* Wo   = fullW ? (bf16_t*)(ws + WQKV) : Wqkv;    // 2 x [1024,2048]
  bf16_t* R0 = (bf16_t*)(ws + wbytes);           // Xcat / mag / attn
  bf16_t* R1 = (bf16_t*)(ws + wbytes + 1*RB);    // Qcat / outc
  bf16_t* Kc = (bf16_t*)(ws + wbytes + 2*RB);    // [NB][4096 interleaved][2048]
  bf16_t* R4 = (bf16_t*)(ws + wbytes + 4*RB);    // Vcat
  bf16_t* R5 = (bf16_t*)(ws + wbytes + 5*RB);    // Vt [NB][2048,2048]

  const int  Mc = NB * 2048;
  const dim3 blk(256);
  const dim3 gqkv(48, Mc / 256, 1);
  const dim3 gsc(32, 8, NB);
  const dim3 gpv(16, 8, NB);
  const dim3 go(16, Mc / 256, 1);
  const dim3 gtr(16, Mc / 64, 2);

  if (fullW) {
    WPack wp;
    for (int p = 0; p < 3; ++p) {
      wp.wa[p] = w_a[p];
      wp.wb[p] = w_b[p];
      wp.oA[p] = Wqkv + (size_t)(2*p)   * 2097152ull;
      wp.oB[p] = Wqkv + (size_t)(2*p+1) * 2097152ull;
    }
    wp.wa[3] = w_a[3]; wp.wb[3] = w_b[3];
    wp.oA[3] = Wo; wp.oB[3] = Wo + 2097152ull;
    pack_w4_kernel<<<dim3(1024, 4), blk, 0, stream>>>(wp, neg_c2);
  }

  for (int c = 0; c < 4 / NB; ++c) {
    const size_t xoff = (size_t)c * NB * 2097152ull;
    pack_x_kernel<<<Mc, blk, 0, stream>>>(xa + xoff, xb + xoff, R0, Mc * 256);

    if (!fullW)
      for (int p = 0; p < 3; ++p)
        pack_w_kernel<<<1024, blk, 0, stream>>>(w_a[p], w_b[p],
            Wqkv + (size_t)(2*p)   * 2097152ull,
            Wqkv + (size_t)(2*p+1) * 2097152ull, neg_c2);

    // fused QKV: [Mc,6144] = Xcat @ Wqkv^T, routed epilogue (interleaved Kc)
    gemm256_kernel<0><<<gqkv, blk, 0, stream>>>(R0, Wqkv, 2048, 2048, 2048, 0, 0,
        R1, Kc, R4, b_a[0], b_b[0], b_a[1], b_b[1], b_a[2], b_b[2], neg_c2);

    // V transpose into R5 = per-batch [Va^T ; Vb^T] (both halves, grid.z=2)
    transpose_v_kernel<<<gtr, blk, 0, stream>>>(R4, R5);

    // fused scores + magnitude: mag = |Qcat_b @ Kc_b^T| pairs -> R0
    gemm256_kernel<1><<<gsc, blk, 0, stream>>>(R1, Kc, 2048, 2048, 2048, 4194304, 8388608,
        R0, nullptr, nullptr, nullptr, nullptr, nullptr, nullptr, nullptr, nullptr, 0.f);

    // softmax over mag -> bf16 attn (in-place over R0)
    softmax_kernel<<<Mc, blk, 0, stream>>>(R0, R0);

    // PV: [out_a|out_b] = attn @ Vt^T -> R1
    gemm256_kernel<2><<<gpv, blk, 0, stream>>>(R0, R5, 2048, 2048, 2048, 4194304, 4194304,
        R1, nullptr, nullptr, nullptr, nullptr, nullptr, nullptr, nullptr, nullptr, 0.f);

    // fused O projection -> fp32 out_a / out_b
    if (!fullW)
      pack_w_kernel<<<1024, blk, 0, stream>>>(w_a[3], w_b[3], Wo, Wo + 2097152ull, neg_c2);
    gemm256_kernel<3><<<go, blk, 0, stream>>>(R1, Wo, 2048, 2048, 2048, 0, 0,
        out + xoff, out + 8388608ull + xoff, nullptr,
        b_a[3], b_b[3], nullptr, nullptr, nullptr, nullptr, 0.f);
  }
}

// Round 19
// 554.855 us; speedup vs baseline: 1.1085x; 1.1085x over previous
//
#include <hip/hip_runtime.h>
#include <math.h>

typedef __bf16 bf16_t;
typedef __attribute__((ext_vector_type(16))) float f32x16;
typedef __attribute__((ext_vector_type(8))) __bf16 v8bf;
typedef __attribute__((ext_vector_type(4))) __bf16 v4bf;

// offset=0 ALWAYS: LDS-DMA offset imm shifts the LDS destination too (R5 post-mortem).
#define GLLDS(g, l)                                                           \
  __builtin_amdgcn_global_load_lds(                                           \
      (const __attribute__((address_space(1))) void*)(g),                     \
      (__attribute__((address_space(3))) void*)(l), 16, 0, 0)
// opaque pointer tie: prevents folding constant steps into the LDS-DMA offset imm.
#define OPQ(p) asm volatile("" : "+v"(p))

// ---------------- diagnostic sentinel ----------------
__global__ void sentinel_kernel(float* o, float v) { o[0] = v; }

// ---------------- pack kernels ----------------
__global__ __launch_bounds__(256) void pack_x_kernel(
    const float* __restrict__ xa, const float* __restrict__ xb,
    bf16_t* __restrict__ xcat, int n4)
{
  int i = blockIdx.x * 256 + threadIdx.x;
  if (i >= n4) return;
  float4 a = reinterpret_cast<const float4*>(xa)[i];
  float4 b = reinterpret_cast<const float4*>(xb)[i];
  long e = (long)i * 4;
  long m = e >> 10;
  int  d = (int)(e & 1023);
  v4bf av = { (bf16_t)a.x, (bf16_t)a.y, (bf16_t)a.z, (bf16_t)a.w };
  v4bf bv = { (bf16_t)b.x, (bf16_t)b.y, (bf16_t)b.z, (bf16_t)b.w };
  *reinterpret_cast<v4bf*>(xcat + m * 2048 + d)        = av;
  *reinterpret_cast<v4bf*>(xcat + m * 2048 + 1024 + d) = bv;
}

// outA[n] = [wa[n,:] | j2*wb[n,:]] ; outB[n] = [wb[n,:] | wa[n,:]]
__global__ __launch_bounds__(256) void pack_w_kernel(
    const float* __restrict__ wa, const float* __restrict__ wb,
    bf16_t* __restrict__ outA, bf16_t* __restrict__ outB, float j2)
{
  int i = blockIdx.x * 256 + threadIdx.x;   // 0..262143, exact
  float4 a = reinterpret_cast<const float4*>(wa)[i];
  float4 b = reinterpret_cast<const float4*>(wb)[i];
  long e = (long)i * 4;
  long n = e >> 10;
  int  k = (int)(e & 1023);
  v4bf av = { (bf16_t)a.x, (bf16_t)a.y, (bf16_t)a.z, (bf16_t)a.w };
  v4bf bv = { (bf16_t)b.x, (bf16_t)b.y, (bf16_t)b.z, (bf16_t)b.w };
  v4bf jb = { (bf16_t)(j2*b.x), (bf16_t)(j2*b.y), (bf16_t)(j2*b.z), (bf16_t)(j2*b.w) };
  *reinterpret_cast<v4bf*>(outA + n * 2048 + k)        = av;
  *reinterpret_cast<v4bf*>(outA + n * 2048 + 1024 + k) = jb;
  *reinterpret_cast<v4bf*>(outB + n * 2048 + k)        = bv;
  *reinterpret_cast<v4bf*>(outB + n * 2048 + 1024 + k) = av;
}

// ---------------- 256x256 pipelined bf16 GEMM (32x32x16 MFMA), C = A @ B^T --
// R13-validated structure (session best: 556.6us total). BK=64, 2-slot ring,
// ONE barrier+vmcnt(0) per K-tile. Ledger: tile t reads slot t&1, stages t+1
// into the other slot; RAW via tile-end vmcnt(0)+barrier; WAR via prior
// barrier. LDS per slot: [A 256x64 | B 256x64]; chunk c of row R stored at
// c^(R&7) (swizzle on GLOBAL source col, rule #21).
// A/B operand: row=lane&31, k=(lane>>5)*8+e (+16/slice). C/D: col=lane&31,
// row=(reg&3)+8*(reg>>2)+4*(lane>>5)  [guide m74/m101; R8-validated].
// EPI 0: QKV-routed, K-buffers INTERLEAVED (row 2t=K1, 2t+1=K2).
// EPI 1: scores with fused magnitude via shfl_xor(1) -> mag bf16.
// EPI 2: PV bf16. EPI 3: O fp32 +bias.
// Closed (falsified) directions: more blocks/CU small waves (R14, -11%);
// fatter waves (R15, 256-VGPR acc -> 1 wave/SIMD, -10%); cross-block overlap
// at neutral LDS ratio (R18, -9%, occupancy unchanged); 10 schedule
// permutations within +-4%; vmcnt depth immaterial (tile 2660cyc >> 900cyc).
template<int EPI>
__global__ __launch_bounds__(512) void gemm256_kernel(
    const bf16_t* __restrict__ A, const bf16_t* __restrict__ B,
    int K, long lda, long ldb, long bsA, long bsB,
    void* __restrict__ o0p, void* __restrict__ o1p, void* __restrict__ o2p,
    const float* __restrict__ bb0, const float* __restrict__ bb1,
    const float* __restrict__ bb2, const float* __restrict__ bb3,
    const float* __restrict__ bb4, const float* __restrict__ bb5,
    float scl)
{
  __shared__ __align__(16) bf16_t lds[65536];  // 2 slots x (A[256][64] | B[256][64])
  const int tid  = threadIdx.x;
  const int wid  = tid >> 6;
  const int lane = tid & 63;
  const int wm = wid >> 2;
  const int wn = wid & 3;

  // natural dispatch (R6 lesson: explicit XCD swizzle doubled FETCH_SIZE)
  const long row0 = (long)blockIdx.y * 256;
  const long col0 = (long)blockIdx.x * 256;
  const int z = blockIdx.z;
  const bf16_t* Ab = A + (long)z * bsA + row0 * lda;
  const bf16_t* Bb = B + (long)z * bsB + col0 * ldb;

  // staging: thread covers row w*8+(l>>3) (+64*i), chunk l&7 of a 64-el row;
  // swizzled GLOBAL source col = ((l&7)^(l>>3))*8; LDS dest stays LINEAR.
  const int srow = wid * 8 + (lane >> 3);
  const int scol = ((lane & 7) ^ (lane >> 3)) * 8;
  const int dbase = wid * 512;   // wave-uniform el offset within a 4096-el section

  // rolling staging pointers (advance 64 el per staged tile, opaque each step)
  const bf16_t* sA0 = Ab + (long)srow * lda + scol;
  const bf16_t* sA1 = Ab + (long)(srow + 64) * lda + scol;
  const bf16_t* sA2 = Ab + (long)(srow + 128) * lda + scol;
  const bf16_t* sA3 = Ab + (long)(srow + 192) * lda + scol;
  const bf16_t* sB0 = Bb + (long)srow * ldb + scol;
  const bf16_t* sB1 = Bb + (long)(srow + 64) * ldb + scol;
  const bf16_t* sB2 = Bb + (long)(srow + 128) * ldb + scol;
  const bf16_t* sB3 = Bb + (long)(srow + 192) * ldb + scol;

  // ds_read bases; stored chunk = (kg2+2s) ^ (r32&7)
  const int r32 = lane & 31;
  const int kg2 = lane >> 5;
  const int r7 = r32 & 7;
  const bf16_t *pAs[4], *pBs[4];
#pragma unroll
  for (int s = 0; s < 4; ++s) {
    const int ch = (((kg2 + 2 * s) ^ r7) & 7) * 8;
    pAs[s] = lds + (wm * 128 + r32) * 64 + ch;
    pBs[s] = lds + 16384 + (wn * 64 + r32) * 64 + ch;
  }

  f32x16 acc[4][2];
#pragma unroll
  for (int i = 0; i < 4; ++i)
#pragma unroll
    for (int j = 0; j < 2; ++j)
#pragma unroll
      for (int e = 0; e < 16; ++e) acc[i][j][e] = 0.f;

  const int T = K >> 6;   // BK=64; K=2048 -> T=32 (T even, T>=4)

  // prologue: stage tile 0 into slot 0 (8 GLLDS), drain, barrier
  GLLDS(sA0, lds + dbase);
  GLLDS(sA1, lds + 4096 + dbase);
  GLLDS(sA2, lds + 8192 + dbase);
  GLLDS(sA3, lds + 12288 + dbase);
  GLLDS(sB0, lds + 16384 + dbase);
  GLLDS(sB1, lds + 16384 + 4096 + dbase);
  GLLDS(sB2, lds + 16384 + 8192 + dbase);
  GLLDS(sB3, lds + 16384 + 12288 + dbase);
  sA0 += 64; sA1 += 64; sA2 += 64; sA3 += 64;
  sB0 += 64; sB1 += 64; sB2 += 64; sB3 += 64;
  OPQ(sA0); OPQ(sA1); OPQ(sA2); OPQ(sA3);
  OPQ(sB0); OPQ(sB1); OPQ(sB2); OPQ(sB3);
  asm volatile("s_waitcnt vmcnt(0)" ::: "memory");
  __builtin_amdgcn_sched_barrier(0);
  __builtin_amdgcn_s_barrier();

  // One K-tile (BK=64): 2 halves of {12 ds_read_b128 + 4 stages + 16 MFMA},
  // single tile-end vmcnt(0)+barrier. U literal 0/1; stages go to slot 1-U.
#define TILE_BODY(U, PF)                                                       \
  {                                                                            \
    const int so_ = (U) * 32768;                                               \
    const int ns_ = (1 - (U)) * 32768;                                         \
    v8bf a_[4][2], b_[2][2];                                                   \
    /* ---- half 1: slices 0,1 ---- */                                         \
    _Pragma("unroll") for (int g = 0; g < 2; ++g)                              \
      _Pragma("unroll") for (int ss = 0; ss < 2; ++ss)                         \
        b_[g][ss] = *reinterpret_cast<const v8bf*>(pBs[ss] + so_ + g * 2048);  \
    _Pragma("unroll") for (int f = 0; f < 4; ++f)                              \
      _Pragma("unroll") for (int ss = 0; ss < 2; ++ss)                         \
        a_[f][ss] = *reinterpret_cast<const v8bf*>(pAs[ss] + so_ + f * 2048);  \
    if (PF) {                                                                  \
      GLLDS(sA0, lds + ns_ + dbase);                                           \
      GLLDS(sA1, lds + ns_ + 4096 + dbase);                                    \
      GLLDS(sA2, lds + ns_ + 8192 + dbase);                                    \
      GLLDS(sA3, lds + ns_ + 12288 + dbase);                                   \
    }                                                                          \
    __builtin_amdgcn_s_setprio(1);                                             \
    _Pragma("unroll") for (int ss = 0; ss < 2; ++ss)                           \
      _Pragma("unroll") for (int f = 0; f < 4; ++f)                            \
        _Pragma("unroll") for (int g = 0; g < 2; ++g)                          \
          acc[f][g] = __builtin_amdgcn_mfma_f32_32x32x16_bf16(a_[f][ss], b_[g][ss], acc[f][g], 0, 0, 0); \
    __builtin_amdgcn_s_setprio(0);                                             \
    /* ---- half 2: slices 2,3 ---- */                                         \
    _Pragma("unroll") for (int g = 0; g < 2; ++g)                              \
      _Pragma("unroll") for (int ss = 0; ss < 2; ++ss)                         \
        b_[g][ss] = *reinterpret_cast<const v8bf*>(pBs[2 + ss] + so_ + g * 2048); \
    _Pragma("unroll") for (int f = 0; f < 4; ++f)                              \
      _Pragma("unroll") for (int ss = 0; ss < 2; ++ss)                         \
        a_[f][ss] = *reinterpret_cast<const v8bf*>(pAs[2 + ss] + so_ + f * 2048); \
    if (PF) {                                                                  \
      GLLDS(sB0, lds + ns_ + 16384 + dbase);                                   \
      GLLDS(sB1, lds + ns_ + 16384 + 4096 + dbase);                            \
      GLLDS(sB2, lds + ns_ + 16384 + 8192 + dbase);                            \
      GLLDS(sB3, lds + ns_ + 16384 + 12288 + dbase);                           \
      sA0 += 64; sA1 += 64; sA2 += 64; sA3 += 64;                              \
      sB0 += 64; sB1 += 64; sB2 += 64; sB3 += 64;                              \
      OPQ(sA0); OPQ(sA1); OPQ(sA2); OPQ(sA3);                                  \
      OPQ(sB0); OPQ(sB1); OPQ(sB2); OPQ(sB3);                                  \
    }                                                                          \
    __builtin_amdgcn_s_setprio(1);                                             \
    _Pragma("unroll") for (int ss = 0; ss < 2; ++ss)                           \
      _Pragma("unroll") for (int f = 0; f < 4; ++f)                            \
        _Pragma("unroll") for (int g = 0; g < 2; ++g)                          \
          acc[f][g] = __builtin_amdgcn_mfma_f32_32x32x16_bf16(a_[f][ss], b_[g][ss], acc[f][g], 0, 0, 0); \
    __builtin_amdgcn_s_setprio(0);                                             \
    asm volatile("s_waitcnt vmcnt(0)" ::: "memory");                           \
    __builtin_amdgcn_sched_barrier(0);                                         \
    __builtin_amdgcn_s_barrier();                                              \
  }

  // main: tiles 0..T-3 (all stage the next tile)
  for (int tb = 0; tb < T - 2; tb += 2) {
    TILE_BODY(0, 1)
    TILE_BODY(1, 1)
  }
  // tail: tile T-2 stages T-1; tile T-1 stages nothing
  TILE_BODY(0, 1)
  TILE_BODY(1, 0)
#undef TILE_BODY

  // epilogue: 32x32 C/D layout col=lane&31, row=(reg&3)+8*(reg>>2)+4*(lane>>5)
  const int hi = lane >> 5;
#pragma unroll
  for (int fm = 0; fm < 4; ++fm) {
#pragma unroll
    for (int fn = 0; fn < 2; ++fn) {
      const f32x16 v = acc[fm][fn];
      const long rowb = row0 + wm * 128 + fm * 32 + 4 * hi;
      const long col  = col0 + wn * 64 + fn * 32 + r32;
      if constexpr (EPI == 0) {
        const int  seg = (int)(col >> 10);   // uniform per (block, wn, fn)
        const long c   = col & 1023;
        bf16_t* Q  = (bf16_t*)o0p;
        bf16_t* Kc = (bf16_t*)o1p;
        bf16_t* Vc = (bf16_t*)o2p;
        switch (seg) {
          case 0: { const float bv = bb0[c];
#pragma unroll
            for (int r = 0; r < 16; ++r) {
              const long row = rowb + (r & 3) + 8 * (r >> 2);
              Q[row * 2048 + c] = (bf16_t)((v[r] + bv) * 0.03125f);
            } } break;
          case 1: { const float bv = bb1[c];
#pragma unroll
            for (int r = 0; r < 16; ++r) {
              const long row = rowb + (r & 3) + 8 * (r >> 2);
              Q[row * 2048 + 1024 + c] = (bf16_t)((v[r] + bv) * 0.03125f);
            } } break;
          case 2: { const float bv = bb2[c];
            // interleaved Kc: row 2t = K1 token t, row 2t+1 = K2 token t
#pragma unroll
            for (int r = 0; r < 16; ++r) {
              const long row = rowb + (r & 3) + 8 * (r >> 2);
              const long kb2 = (row >> 11) * 8388608 + (row & 2047) * 4096;
              const float w = v[r] + bv;
              Kc[kb2 + c]               = (bf16_t)w;          // K1 = [Ka | .]
              Kc[kb2 + 2048 + 1024 + c] = (bf16_t)w;          // K2 = [. | Ka]
            } } break;
          case 3: { const float bv = bb3[c];
#pragma unroll
            for (int r = 0; r < 16; ++r) {
              const long row = rowb + (r & 3) + 8 * (r >> 2);
              const long kb2 = (row >> 11) * 8388608 + (row & 2047) * 4096;
              const float w = v[r] + bv;
              Kc[kb2 + 2048 + c] = (bf16_t)w;                 // K2 = [Kb | .]
              Kc[kb2 + 1024 + c] = (bf16_t)(scl * w);         // K1 = [. | -c2*Kb]
            } } break;
          case 4: { const float bv = bb4[c];
#pragma unroll
            for (int r = 0; r < 16; ++r) {
              const long row = rowb + (r & 3) + 8 * (r >> 2);
              Vc[row * 2048 + c] = (bf16_t)(v[r] + bv);
            } } break;
          default: { const float bv = bb5[c];
#pragma unroll
            for (int r = 0; r < 16; ++r) {
              const long row = rowb + (r & 3) + 8 * (r >> 2);
              Vc[row * 2048 + 1024 + c] = (bf16_t)(v[r] + bv);
            } } break;
        }
      } else if constexpr (EPI == 1) {
        // interleaved scores: col even = sa(s, col>>1), odd = sb. Pair lanes
        // (l, l^1) share rowb and token; fuse magnitude via shfl_xor.
        bf16_t* dst = (bf16_t*)o0p;
        const long tt = col >> 1;
#pragma unroll
        for (int r = 0; r < 16; ++r) {
          const long row = rowb + (r & 3) + 8 * (r >> 2);
          const float x = v[r];
          const float p = __shfl_xor(x, 1);
          const float mg = sqrtf(x * x + p * p);
          if (!(lane & 1))
            dst[(long)z * 4194304 + row * 2048 + tt] = (bf16_t)mg;
        }
      } else if constexpr (EPI == 2) {
#pragma unroll
        for (int r = 0; r < 16; ++r) {
          const long row = rowb + (r & 3) + 8 * (r >> 2);
          ((bf16_t*)o0p)[(long)z * 4194304 + row * 2048 + col] = (bf16_t)v[r];
        }
      } else {
        const int  seg = (int)(col >> 10);
        const long c   = col & 1023;
        float* dst = seg ? (float*)o1p : (float*)o0p;
        const float bv = seg ? bb1[c] : bb0[c];
#pragma unroll
        for (int r = 0; r < 16; ++r) {
          const long row = rowb + (r & 3) + 8 * (r >> 2);
          dst[row * 1024 + c] = v[r] + bv;
        }
      }
    }
  }
}

// ---------------- V transpose (fused both halves via blockIdx.z) ----------------
__global__ __launch_bounds__(256) void transpose_v_kernel(
    const bf16_t* __restrict__ src, bf16_t* __restrict__ dst)
{
  __shared__ bf16_t t[64][65];
  const int tid = threadIdx.x;
  const int off = blockIdx.z * 1024;
  const long c0 = (long)blockIdx.x * 64;
  const long g0 = (long)blockIdx.y * 64;
#pragma unroll
  for (int it = 0; it < 16; ++it) {
    int idx = it * 256 + tid;
    int r = idx >> 6, c = idx & 63;
    t[r][c] = src[(g0 + r) * 2048 + off + c0 + c];
  }
  __syncthreads();
  const long b  = g0 >> 11;
  const long t0 = g0 & 2047;
#pragma unroll
  for (int it = 0; it < 16; ++it) {
    int idx = it * 256 + tid;
    int nr = idx >> 6, tc = idx & 63;
    dst[b * 4194304 + (off + c0 + nr) * 2048 + t0 + tc] = t[tc][nr];
  }
}

// ---------------- softmax over precomputed magnitude (in-place safe) ----------------
__global__ __launch_bounds__(256) void softmax_kernel(
    const bf16_t* __restrict__ mag, bf16_t* __restrict__ attn)
{
  const int tid = threadIdx.x;
  const long base = (long)blockIdx.x * 2048;
  v4bf m0 = *reinterpret_cast<const v4bf*>(mag + base + tid * 4);
  v4bf m1 = *reinterpret_cast<const v4bf*>(mag + base + 1024 + tid * 4);
  float r[8];
#pragma unroll
  for (int k = 0; k < 4; ++k) r[k] = (float)m0[k];
#pragma unroll
  for (int k = 0; k < 4; ++k) r[4 + k] = (float)m1[k];
  float m = r[0];
#pragma unroll
  for (int k = 1; k < 8; ++k) m = fmaxf(m, r[k]);
#pragma unroll
  for (int off = 32; off > 0; off >>= 1) m = fmaxf(m, __shfl_xor(m, off));
  __shared__ float red[8];
  if ((tid & 63) == 0) red[tid >> 6] = m;
  __syncthreads();
  m = fmaxf(fmaxf(red[0], red[1]), fmaxf(red[2], red[3]));
  float p[8], s = 0.f;
#pragma unroll
  for (int k = 0; k < 8; ++k) { p[k] = __expf(r[k] - m); s += p[k]; }
#pragma unroll
  for (int off = 32; off > 0; off >>= 1) s += __shfl_xor(s, off);
  if ((tid & 63) == 0) red[4 + (tid >> 6)] = s;
  __syncthreads();
  const float inv = 1.f / (red[4] + red[5] + red[6] + red[7]);
  v4bf o0 = { (bf16_t)(p[0]*inv), (bf16_t)(p[1]*inv), (bf16_t)(p[2]*inv), (bf16_t)(p[3]*inv) };
  v4bf o1 = { (bf16_t)(p[4]*inv), (bf16_t)(p[5]*inv), (bf16_t)(p[6]*inv), (bf16_t)(p[7]*inv) };
  *reinterpret_cast<v4bf*>(attn + base + tid * 4)        = o0;
  *reinterpret_cast<v4bf*>(attn + base + 1024 + tid * 4) = o1;
}

// ---------------- host ----------------
extern "C" void kernel_launch(void* const* d_in, const int* in_sizes, int n_in,
                              void* d_out, int out_size, void* d_ws, size_t ws_size,
                              hipStream_t stream)
{
  (void)in_sizes; (void)n_in; (void)out_size;
  const float* xa = (const float*)d_in[0];
  const float* xb = (const float*)d_in[1];
  const float *w_a[4], *w_b[4], *b_a[4], *b_b[4];
  for (int p = 0; p < 4; ++p) {
    w_a[p] = (const float*)d_in[2 + p*4 + 0];
    w_b[p] = (const float*)d_in[2 + p*4 + 1];
    b_a[p] = (const float*)d_in[2 + p*4 + 2];
    b_b[p] = (const float*)d_in[2 + p*4 + 3];
  }
  float* out = (float*)d_out;
  const float neg_c2 = (float)(-cos(2.0));

  // ---- adaptive workspace tiers (identical thresholds to passing rounds) ----
  const size_t WFULL = 33554432ull;   // 8 weight slots of [1024,2048] bf16
  const size_t WQKV  = 25165824ull;   // 6 slots (low tier: O re-packed over QKV)
  int NB = 0; bool fullW = true;
  if      (ws_size >= WFULL + 6ull * 4ull * 8388608ull) NB = 4;               // 224 MiB
  else if (ws_size >= WFULL + 6ull * 2ull * 8388608ull) NB = 2;               // 128 MiB
  else if (ws_size >= WFULL + 6ull * 1ull * 8388608ull) NB = 1;               //  80 MiB
  else if (ws_size >= WQKV  + 6ull * 1ull * 8388608ull) { NB = 1; fullW = false; } // 72 MiB
  else { sentinel_kernel<<<1, 1, 0, stream>>>(out, (float)ws_size); return; }

  char* ws = (char*)d_ws;
  const size_t wbytes = fullW ? WFULL : WQKV;
  const size_t RB = (size_t)NB * 8388608ull;
  bf16_t* Wqkv = (bf16_t*)ws;                            // 6 x [1024,2048]
  bf16_t* Wo   = fullW ? (bf16_t*)(ws + WQKV) : Wqkv;    // 2 x [1024,2048]
  bf16_t* R0 = (bf16_t*)(ws + wbytes);           // Xcat / mag / attn
  bf16_t* R1 = (bf16_t*)(ws + wbytes + 1*RB);    // Qcat / outc
  bf16_t* Kc = (bf16_t*)(ws + wbytes + 2*RB);    // [NB][4096 interleaved][2048]
  bf16_t* R4 = (bf16_t*)(ws + wbytes + 4*RB);    // Vcat
  bf16_t* R5 = (bf16_t*)(ws + wbytes + 5*RB);    // Vt [NB][2048,2048]

  const int  Mc = NB * 2048;
  const dim3 blk(256);
  const dim3 blk512(512);
  const dim3 gqkv(24, Mc / 256, 1);
  const dim3 gsc(16, 8, NB);
  const dim3 gpv(8, 8, NB);
  const dim3 go(8, Mc / 256, 1);
  const dim3 gtr(16, Mc / 64, 2);

  if (fullW) {
    for (int p = 0; p < 3; ++p)
      pack_w_kernel<<<1024, blk, 0, stream>>>(w_a[p], w_b[p],
          Wqkv + (size_t)(2*p)   * 2097152ull,
          Wqkv + (size_t)(2*p+1) * 2097152ull, neg_c2);
    pack_w_kernel<<<1024, blk, 0, stream>>>(w_a[3], w_b[3],
        Wo, Wo + 2097152ull, neg_c2);
  }

  for (int c = 0; c < 4 / NB; ++c) {
    const size_t xoff = (size_t)c * NB * 2097152ull;
    pack_x_kernel<<<Mc, blk, 0, stream>>>(xa + xoff, xb + xoff, R0, Mc * 256);

    if (!fullW)
      for (int p = 0; p < 3; ++p)
        pack_w_kernel<<<1024, blk, 0, stream>>>(w_a[p], w_b[p],
            Wqkv + (size_t)(2*p)   * 2097152ull,
            Wqkv + (size_t)(2*p+1) * 2097152ull, neg_c2);

    // fused QKV: [Mc,6144] = Xcat @ Wqkv^T, routed epilogue (interleaved Kc)
    gemm256_kernel<0><<<gqkv, blk512, 0, stream>>>(R0, Wqkv, 2048, 2048, 2048, 0, 0,
        R1, Kc, R4, b_a[0], b_b[0], b_a[1], b_b[1], b_a[2], b_b[2], neg_c2);

    // V transpose into R5 = per-batch [Va^T ; Vb^T] (both halves, grid.z=2)
    transpose_v_kernel<<<gtr, blk, 0, stream>>>(R4, R5);

    // fused scores + magnitude: mag = |Qcat_b @ Kc_b^T| pairs -> R0
    gemm256_kernel<1><<<gsc, blk512, 0, stream>>>(R1, Kc, 2048, 2048, 2048, 4194304, 8388608,
        R0, nullptr, nullptr, nullptr, nullptr, nullptr, nullptr, nullptr, nullptr, 0.f);

    // softmax over mag -> bf16 attn (in-place over R0)
    softmax_kernel<<<Mc, blk, 0, stream>>>(R0, R0);

    // PV: [out_a|out_b] = attn @ Vt^T -> R1
    gemm256_kernel<2><<<gpv, blk512, 0, stream>>>(R0, R5, 2048, 2048, 2048, 4194304, 4194304,
        R1, nullptr, nullptr, nullptr, nullptr, nullptr, nullptr, nullptr, nullptr, 0.f);

    // fused O projection -> fp32 out_a / out_b
    if (!fullW)
      pack_w_kernel<<<1024, blk, 0, stream>>>(w_a[3], w_b[3], Wo, Wo + 2097152ull, neg_c2);
    gemm256_kernel<3><<<go, blk512, 0, stream>>>(R1, Wo, 2048, 2048, 2048, 0, 0,
        out + xoff, out + 8388608ull + xoff, nullptr,
        b_a[3], b_b[3], nullptr, nullptr, nullptr, nullptr, 0.f);
  }
}